// Round 4
// baseline (822.668 us; speedup 1.0000x reference)
//
#include <hip/hip_runtime.h>

typedef unsigned short u16;
typedef unsigned int u32;
typedef __bf16 bf16x8 __attribute__((ext_vector_type(8)));
typedef float f32x4 __attribute__((ext_vector_type(4)));
typedef u32 u32x4 __attribute__((ext_vector_type(4)));
typedef u16 u16x4 __attribute__((ext_vector_type(4)));

#define NH 2048
#define BATCH 256
#define NIN 1024
#define NOUT 256
#define LAY 4
#define TSS 32
#define BK 64

#define WAITVM(N) asm volatile("s_waitcnt vmcnt(" #N ")" ::: "memory")

__device__ __forceinline__ u16 f2bf(float f) {
  u32 u = __builtin_bit_cast(u32, f);
  u = (u + 0x7FFFu + ((u >> 16) & 1u)) >> 16;
  return (u16)u;
}
__device__ __forceinline__ float bf2f(u16 h) {
  u32 u = ((u32)h) << 16;
  return __builtin_bit_cast(float, u);
}

// sin for |x| <= ~6, abs err < ~4e-6 (degree-9 odd, pi range reduction)
__device__ __forceinline__ float fast_sin(float x) {
  float k = __builtin_rintf(x * 0.3183098861837907f);
  float r = __builtin_fmaf(k, -3.14159274101257324f, x);
  r = __builtin_fmaf(k, 8.742277657347586e-08f, r);
  float s = r * r;
  float p = __builtin_fmaf(s, 2.75573192e-06f, -1.98412698e-04f);
  p = __builtin_fmaf(s, p, 8.33333333e-03f);
  p = __builtin_fmaf(s, p, -1.66666667e-01f);
  p = r + r * s * p;
  int ki = (int)k;
  return (ki & 1) ? -p : p;
}

__device__ __forceinline__ bf16x8 ld_frag(const u16* p) {
  u32x4 r = *(const u32x4*)p;
  return __builtin_bit_cast(bf16x8, r);
}

__device__ __forceinline__ f32x4 mfma16(bf16x8 a, bf16x8 b, f32x4 c) {
  return __builtin_amdgcn_mfma_f32_16x16x32_bf16(a, b, c, 0, 0, 0);
}

__device__ __forceinline__ void gload16(const u16* g, u16* lds) {
  __builtin_amdgcn_global_load_lds(
      (__attribute__((address_space(1))) u32*)g,
      (__attribute__((address_space(3))) u32*)lds, 16, 0, 0);
}

// ---------------- pack / convert kernels ----------------

__global__ __launch_bounds__(256) void k_cvt(const float* __restrict__ in,
                                             u16* __restrict__ out, int n4) {
  int i = blockIdx.x * 256 + threadIdx.x;
  if (i >= n4) return;
  f32x4 v = ((const f32x4*)in)[i];
  u16x4 o;
  #pragma unroll
  for (int j = 0; j < 4; j++) o[j] = f2bf(v[j]);
  ((u16x4*)out)[i] = o;
}

__global__ __launch_bounds__(256) void k_split2(const float* __restrict__ in,
                                                u16* __restrict__ hi,
                                                u16* __restrict__ lo, int n4) {
  int i = blockIdx.x * 256 + threadIdx.x;
  if (i >= n4) return;
  f32x4 v = ((const f32x4*)in)[i];
  u16x4 hv, lv;
  #pragma unroll
  for (int j = 0; j < 4; j++) {
    u16 h = f2bf(v[j]);
    hv[j] = h;
    lv[j] = f2bf(v[j] - bf2f(h));
  }
  ((u16x4*)hi)[i] = hv;
  ((u16x4*)lo)[i] = lv;
}

// ---------------- main GEMM: 128x128 tile, BK=64, depth-4, 1 barrier/iter ---
// LDS tile [128 rows][64 bf16 = 128 B], swizzle: 16B-chunk ^= (row & 7),
// applied on the global SOURCE address (linear LDS dest) and on ds_read.
// Pipeline: 4 LDS buffers, 3 tiles in flight; per iter:
//   vmcnt(16) -> s_barrier -> stage(kb+3 into buf[(kb-1)%4]) -> compute(cur).
// Safety: at iter kb's barrier every wave completed its ds_reads of
// buf[(kb-1)%4] (lgkmcnt drains before the consuming MFMAs, which issue
// before the barrier), so restaging it needs no second barrier.
// Tail peeled with vmcnt(16/8/0).
// Block decode (low->high): l, ks, nt, mt -> each (l,ks) W-half owned by one
// XCD, mt/nt sharers on the same XCD (W-half = 4 MB = one XCD L2).

struct GemmArgs {
  const u16* A[4];
  const u16* B[4];
  void* G;
  int ldA, ldB, kiters, nl;
};

template <int OBF>
__global__ __launch_bounds__(256) void k_gemm(GemmArgs args) {
  __shared__ alignas(16) u16 Ab[4][128 * BK];
  __shared__ alignas(16) u16 Bb[4][128 * BK];

  int bid = blockIdx.x;
  int nl = args.nl;
  int l = bid % nl;
  int t1 = bid / nl;
  int ks = t1 & 1;
  int t2 = t1 >> 1;
  int nt = t2 & 15;
  int mt = t2 >> 4;

  int tid = threadIdx.x;
  int w = tid >> 6, lane = tid & 63;
  int l15 = lane & 15, l4 = lane >> 4;
  int ldA = args.ldA, ldB = args.ldB;
  int kiters = args.kiters;

  const u16* Ag = args.A[l] + (size_t)(mt * 128) * ldA + ks * (kiters * BK);
  const u16* Bg = args.B[l] + (size_t)(nt * 128) * ldB + ks * (kiters * BK);

  // staging: wave w stages rows [w*32, w*32+32), 4 chunks of 8 rows each.
  // LDS linear byte L = w*4096 + j*1024 + lane*16 -> row = w*32+j*8+(lane>>3),
  // chunkpos = lane&7; source chunk = chunkpos ^ (row&7) = (lane&7)^(lane>>3).
  int srow = w * 32 + (lane >> 3);
  int csrc = ((lane & 7) ^ (lane >> 3)) * 8;
  size_t agoff[4], bgoff[4];
  int lbase[4];
  #pragma unroll
  for (int j = 0; j < 4; j++) {
    agoff[j] = (size_t)(srow + j * 8) * ldA + csrc;
    bgoff[j] = (size_t)(srow + j * 8) * ldB + csrc;
    lbase[j] = w * 2048 + j * 512;  // elems
  }

  int wr = w >> 1, wc = w & 1;

  f32x4 zero = {0.f, 0.f, 0.f, 0.f};
  f32x4 acc[4][4];
  #pragma unroll
  for (int m = 0; m < 4; m++)
    #pragma unroll
    for (int n = 0; n < 4; n++) acc[m][n] = zero;

  auto stage = [&](int bufi, int kb) {
    int k0 = kb * BK;
    #pragma unroll
    for (int j = 0; j < 4; j++) {
      gload16(Ag + agoff[j] + k0, &Ab[bufi][lbase[j]]);
      gload16(Bg + bgoff[j] + k0, &Bb[bufi][lbase[j]]);
    }
  };
  auto compute = [&](int bufi) {
    #pragma unroll
    for (int kk = 0; kk < 2; kk++) {
      int swz = ((kk * 4 + l4) ^ (l15 & 7)) * 8;
      bf16x8 a[4], b[4];
      #pragma unroll
      for (int m = 0; m < 4; m++)
        a[m] = ld_frag(&Ab[bufi][(wr * 64 + m * 16 + l15) * BK + swz]);
      #pragma unroll
      for (int n = 0; n < 4; n++)
        b[n] = ld_frag(&Bb[bufi][(wc * 64 + n * 16 + l15) * BK + swz]);
      #pragma unroll
      for (int m = 0; m < 4; m++)
        #pragma unroll
        for (int n = 0; n < 4; n++)
          acc[m][n] = mfma16(a[m], b[n], acc[m][n]);
    }
  };

  // prologue: 3 tiles in flight (24 loads/wave)
  stage(0, 0);
  stage(1, 1);
  stage(2, 2);

  int cur = 0;
  for (int kb = 0; kb < kiters - 3; kb++) {
    WAITVM(16);                        // this wave's buf[cur] loads landed
    __builtin_amdgcn_s_barrier();      // all waves' buf[cur] loads landed;
                                       // all waves done reading buf[cur+3]
    stage((cur + 3) & 3, kb + 3);      // issue next tile BEFORE compute
    compute(cur);
    cur = (cur + 1) & 3;
  }
  // tail: outstanding 24 -> 16 -> 8 -> 0
  WAITVM(16);
  __builtin_amdgcn_s_barrier();
  compute(cur);
  cur = (cur + 1) & 3;
  WAITVM(8);
  __builtin_amdgcn_s_barrier();
  compute(cur);
  cur = (cur + 1) & 3;
  WAITVM(0);
  __builtin_amdgcn_s_barrier();
  compute(cur);

  size_t obase = ((size_t)(ks * nl + l) * BATCH + mt * 128) * NH + nt * 128;
  if (OBF) {
    u16* Go = (u16*)args.G + obase;
    #pragma unroll
    for (int m = 0; m < 4; m++) {
      int row = wr * 64 + m * 16 + l4 * 4;
      #pragma unroll
      for (int n = 0; n < 4; n++) {
        int col = wc * 64 + n * 16 + l15;
        #pragma unroll
        for (int r = 0; r < 4; r++)
          Go[(size_t)(row + r) * NH + col] = f2bf(acc[m][n][r]);
      }
    }
  } else {
    float* Go = (float*)args.G + obase;
    #pragma unroll
    for (int m = 0; m < 4; m++) {
      int row = wr * 64 + m * 16 + l4 * 4;
      #pragma unroll
      for (int n = 0; n < 4; n++) {
        int col = wc * 64 + n * 16 + l15;
        #pragma unroll
        for (int r = 0; r < 4; r++)
          Go[(size_t)(row + r) * NH + col] = acc[m][n][r];
      }
    }
  }
}

// ---------------- element-wise sin chain ----------------
// hout[l] = sin(hout[l-1] + G0[l] + G1[l] + b[l]); G partials are bf16
__global__ __launch_bounds__(256) void k_chain(const u16* __restrict__ Gp,
                                               const float* __restrict__ x_in,
                                               const float* __restrict__ brec,
                                               u16* __restrict__ hout) {
  int i = blockIdx.x * 256 + threadIdx.x;  // 131072 threads, 4 elems each
  int e = i * 4;
  int col = e & (NH - 1);
  f32x4 pre = *(const f32x4*)(x_in + e);
  #pragma unroll
  for (int l = 0; l < LAY; l++) {
    u16x4 g0 = *(const u16x4*)(Gp + (size_t)l * (BATCH * NH) + e);
    u16x4 g1 = *(const u16x4*)(Gp + (size_t)(LAY + l) * (BATCH * NH) + e);
    f32x4 bb = *(const f32x4*)(brec + l * NH + col);
    u16x4 hv;
    #pragma unroll
    for (int j = 0; j < 4; j++) {
      float v = fast_sin(pre[j] + bf2f(g0[j]) + bf2f(g1[j]) + bb[j]);
      pre[j] = v;
      hv[j] = f2bf(v);
    }
    *(u16x4*)(hout + (size_t)l * (BATCH * NH) + e) = hv;
  }
}

// x_in = sum of 6 partial slices + bias (fp32 partials)
__global__ __launch_bounds__(256) void k_xin_fin(const float* __restrict__ Gp2,
                                                 const float* __restrict__ bin,
                                                 float* __restrict__ x_in) {
  int i = blockIdx.x * 256 + threadIdx.x;
  int e = i * 4;
  int col = e & (NH - 1);
  f32x4 s = *(const f32x4*)(bin + col);
  #pragma unroll
  for (int t = 0; t < 6; t++)
    s += *(const f32x4*)(Gp2 + (size_t)t * (BATCH * NH) + e);
  *(f32x4*)(x_in + e) = s;
}

// ---------------- output projection: out = h3 @ (Wh+Wl)^T + b ----------------
__global__ __launch_bounds__(64) void k_gemm_out(const u16* __restrict__ h3,
                                                 const u16* __restrict__ Wh,
                                                 const u16* __restrict__ Wl,
                                                 const float* __restrict__ bout,
                                                 float* __restrict__ out) {
  int bid = blockIdx.x;  // 128 = 8 mt x 16 nt
  int mt = bid & 7, nt = bid >> 3;
  int lane = threadIdx.x;
  int l15 = lane & 15, l4 = lane >> 4;
  f32x4 zero = {0.f, 0.f, 0.f, 0.f};
  f32x4 acc0 = zero, acc1 = zero;
  const u16* a0p = h3 + (size_t)(mt * 32 + l15) * NH + l4 * 8;
  const u16* a1p = a0p + 16 * NH;
  const u16* bhp = Wh + (size_t)(nt * 16 + l15) * NH + l4 * 8;
  const u16* blp = Wl + (size_t)(nt * 16 + l15) * NH + l4 * 8;
  for (int kb = 0; kb < 64; kb++) {
    bf16x8 a0 = ld_frag(a0p + kb * 32);
    bf16x8 a1 = ld_frag(a1p + kb * 32);
    bf16x8 bh = ld_frag(bhp + kb * 32);
    bf16x8 bl = ld_frag(blp + kb * 32);
    acc0 = mfma16(a0, bh, acc0);
    acc0 = mfma16(a0, bl, acc0);
    acc1 = mfma16(a1, bh, acc1);
    acc1 = mfma16(a1, bl, acc1);
  }
  float bo = bout[nt * 16 + l15];
  #pragma unroll
  for (int r = 0; r < 4; r++) {
    out[(size_t)(mt * 32 + l4 * 4 + r) * NOUT + nt * 16 + l15] = acc0[r] + bo;
    out[(size_t)(mt * 32 + 16 + l4 * 4 + r) * NOUT + nt * 16 + l15] = acc1[r] + bo;
  }
}

// ---------------- host ----------------

extern "C" void kernel_launch(void* const* d_in, const int* in_sizes, int n_in,
                              void* d_out, int out_size, void* d_ws, size_t ws_size,
                              hipStream_t stream) {
  const float* X     = (const float*)d_in[0];
  const float* Winw  = (const float*)d_in[1];
  const float* Winb  = (const float*)d_in[2];
  const float* Wrw   = (const float*)d_in[3];
  const float* Wrb   = (const float*)d_in[4];
  const float* Woutw = (const float*)d_in[5];
  const float* Woutb = (const float*)d_in[6];
  float* out = (float*)d_out;

  char* ws = (char*)d_ws;
  u16* Wb     = (u16*)(ws);                    // 32 MB  bf16 W_rec
  u16* h0     = (u16*)(ws + 33554432);         // 4 MB
  u16* h1     = (u16*)(ws + 37748736);         // 4 MB
  float* xin  = (float*)(ws + 41943040);       // 2 MB
  u16* Gp     = (u16*)(ws + 44040192);         // 8 MB bf16 (2 ks x 4 l)
  float* Gp2  = (float*)(ws + 52428800);       // 12 MB fp32 (2 ks x 3 terms)
  u16* Xhi    = (u16*)(ws + 65011712);         // 512 KB
  u16* Xlo    = (u16*)(ws + 65536000);         // 512 KB
  u16* Winh   = (u16*)(ws + 66060288);         // 4 MB
  u16* Winl   = (u16*)(ws + 70254592);         // 4 MB
  u16* Wouth  = (u16*)(ws + 74448896);         // 1 MB
  u16* Woutl  = (u16*)(ws + 75497472);         // 1 MB -> end 76546048

  // pack weights (every call; stateless)
  k_cvt<<<16384, 256, 0, stream>>>(Wrw, Wb, 4194304);
  k_split2<<<256, 256, 0, stream>>>(X, Xhi, Xlo, 65536);
  k_split2<<<2048, 256, 0, stream>>>(Winw, Winh, Winl, 524288);
  k_split2<<<512, 256, 0, stream>>>(Woutw, Wouth, Woutl, 131072);
  hipMemsetAsync(h0, 0, 4194304, stream);

  // x_in = X @ W_in^T (+bias), 3-term bf16 split, fp32 partials
  GemmArgs ax;
  ax.A[0] = Xhi; ax.A[1] = Xhi; ax.A[2] = Xlo; ax.A[3] = Xhi;
  ax.B[0] = Winh; ax.B[1] = Winl; ax.B[2] = Winh; ax.B[3] = Winh;
  ax.G = Gp2; ax.ldA = NIN; ax.ldB = NIN; ax.kiters = 8; ax.nl = 3;
  k_gemm<0><<<192, 256, 0, stream>>>(ax);
  k_xin_fin<<<512, 256, 0, stream>>>(Gp2, Winb, xin);

  u16* hin = h0;
  u16* hout = h1;
  for (int t = 0; t < TSS; t++) {
    GemmArgs ar;
    for (int l = 0; l < 4; l++) {
      ar.A[l] = hin + (size_t)l * (BATCH * NH);
      ar.B[l] = Wb + (size_t)l * (NH * NH);
    }
    ar.G = Gp; ar.ldA = NH; ar.ldB = NH; ar.kiters = 16; ar.nl = 4;
    k_gemm<1><<<256, 256, 0, stream>>>(ar);
    k_chain<<<512, 256, 0, stream>>>(Gp, xin, Wrb, hout);
    u16* tmp = hin; hin = hout; hout = tmp;
  }

  k_gemm_out<<<128, 64, 0, stream>>>(hin + (size_t)3 * (BATCH * NH), Wouth, Woutl,
                                     Woutb, out);
}

// Round 5
// 690.375 us; speedup vs baseline: 1.1916x; 1.1916x over previous
//
#include <hip/hip_runtime.h>

typedef unsigned short u16;
typedef unsigned int u32;
typedef __bf16 bf16x8 __attribute__((ext_vector_type(8)));
typedef float f32x4 __attribute__((ext_vector_type(4)));
typedef u32 u32x4 __attribute__((ext_vector_type(4)));
typedef u16 u16x4 __attribute__((ext_vector_type(4)));

#define NH 2048
#define BATCH 256
#define NIN 1024
#define NOUT 256
#define LAY 4
#define TSS 32
#define BK 64

#define WAITVM(N) asm volatile("s_waitcnt vmcnt(" #N ")" ::: "memory")

__device__ __forceinline__ u16 f2bf(float f) {
  u32 u = __builtin_bit_cast(u32, f);
  u = (u + 0x7FFFu + ((u >> 16) & 1u)) >> 16;
  return (u16)u;
}
__device__ __forceinline__ float bf2f(u16 h) {
  u32 u = ((u32)h) << 16;
  return __builtin_bit_cast(float, u);
}

// sin for |x| <= ~6, abs err < ~4e-6 (degree-9 odd, pi range reduction)
__device__ __forceinline__ float fast_sin(float x) {
  float k = __builtin_rintf(x * 0.3183098861837907f);
  float r = __builtin_fmaf(k, -3.14159274101257324f, x);
  r = __builtin_fmaf(k, 8.742277657347586e-08f, r);
  float s = r * r;
  float p = __builtin_fmaf(s, 2.75573192e-06f, -1.98412698e-04f);
  p = __builtin_fmaf(s, p, 8.33333333e-03f);
  p = __builtin_fmaf(s, p, -1.66666667e-01f);
  p = r + r * s * p;
  int ki = (int)k;
  return (ki & 1) ? -p : p;
}

__device__ __forceinline__ bf16x8 ld_frag(const u16* p) {
  u32x4 r = *(const u32x4*)p;
  return __builtin_bit_cast(bf16x8, r);
}

__device__ __forceinline__ f32x4 mfma16(bf16x8 a, bf16x8 b, f32x4 c) {
  return __builtin_amdgcn_mfma_f32_16x16x32_bf16(a, b, c, 0, 0, 0);
}

__device__ __forceinline__ void gload16(const u16* g, u16* lds) {
  __builtin_amdgcn_global_load_lds(
      (__attribute__((address_space(1))) u32*)g,
      (__attribute__((address_space(3))) u32*)lds, 16, 0, 0);
}

// ---------------- pack / convert kernels ----------------

__global__ __launch_bounds__(256) void k_cvt(const float* __restrict__ in,
                                             u16* __restrict__ out, int n4) {
  int i = blockIdx.x * 256 + threadIdx.x;
  if (i >= n4) return;
  f32x4 v = ((const f32x4*)in)[i];
  u16x4 o;
  #pragma unroll
  for (int j = 0; j < 4; j++) o[j] = f2bf(v[j]);
  ((u16x4*)out)[i] = o;
}

__global__ __launch_bounds__(256) void k_split2(const float* __restrict__ in,
                                                u16* __restrict__ hi,
                                                u16* __restrict__ lo, int n4) {
  int i = blockIdx.x * 256 + threadIdx.x;
  if (i >= n4) return;
  f32x4 v = ((const f32x4*)in)[i];
  u16x4 hv, lv;
  #pragma unroll
  for (int j = 0; j < 4; j++) {
    u16 h = f2bf(v[j]);
    hv[j] = h;
    lv[j] = f2bf(v[j] - bf2f(h));
  }
  ((u16x4*)hi)[i] = hv;
  ((u16x4*)lo)[i] = lv;
}

// ---------------- main GEMM: 128x128 tile, BK=64, depth-2, 2 blocks/CU ------
// LDS tile [128 rows][64 bf16 = 128 B], swizzle: 16B-chunk ^= (row & 7),
// applied on the global SOURCE address (linear LDS dest) and on ds_read.
// Occupancy design: 2 LDS buffers = 64 KB/block -> 2 blocks/CU (8 waves/CU).
// Per-block pipeline is shallow (1 compute phase of cover); the co-resident
// block hides the vmcnt/barrier drains (m114 wave-level overlap).
// Schedule (r3-proven 2-barrier form):
//   WAITVM(8) -> s_barrier -> compute(cur) -> s_barrier -> stage(cur, kb+2).
// Block decode (low->high): l, ks, nt, mt -> each XCD owns 2 W K-slices
// (2 MB each) of one layer = 4 MB = its L2; mt/nt sharers on the same XCD.

struct GemmArgs {
  const u16* A[4];
  const u16* B[4];
  void* G;
  int ldA, ldB, kiters, nl;
};

template <int OBF, int NKS>
__global__ __launch_bounds__(256, 2) void k_gemm(GemmArgs args) {
  __shared__ alignas(16) u16 Ab[2][128 * BK];
  __shared__ alignas(16) u16 Bb[2][128 * BK];

  int bid = blockIdx.x;
  int nl = args.nl;
  int l = bid % nl;
  int t1 = bid / nl;
  int ks = t1 & (NKS - 1);
  int t2 = t1 / NKS;
  int nt = t2 & 15;
  int mt = t2 >> 4;

  int tid = threadIdx.x;
  int w = tid >> 6, lane = tid & 63;
  int l15 = lane & 15, l4 = lane >> 4;
  int ldA = args.ldA, ldB = args.ldB;
  int kiters = args.kiters;

  const u16* Ag = args.A[l] + (size_t)(mt * 128) * ldA + ks * (kiters * BK);
  const u16* Bg = args.B[l] + (size_t)(nt * 128) * ldB + ks * (kiters * BK);

  // staging: wave w stages rows [w*32, w*32+32), 4 chunks of 8 rows each.
  // LDS linear byte L = w*4096 + j*1024 + lane*16 -> row = w*32+j*8+(lane>>3),
  // chunkpos = lane&7; source chunk = chunkpos ^ (row&7) = (lane&7)^(lane>>3).
  int srow = w * 32 + (lane >> 3);
  int csrc = ((lane & 7) ^ (lane >> 3)) * 8;
  size_t agoff[4], bgoff[4];
  int lbase[4];
  #pragma unroll
  for (int j = 0; j < 4; j++) {
    agoff[j] = (size_t)(srow + j * 8) * ldA + csrc;
    bgoff[j] = (size_t)(srow + j * 8) * ldB + csrc;
    lbase[j] = w * 2048 + j * 512;  // elems
  }

  int wr = w >> 1, wc = w & 1;

  f32x4 zero = {0.f, 0.f, 0.f, 0.f};
  f32x4 acc[4][4];
  #pragma unroll
  for (int m = 0; m < 4; m++)
    #pragma unroll
    for (int n = 0; n < 4; n++) acc[m][n] = zero;

  auto stage = [&](int bufi, int kb) {
    int k0 = kb * BK;
    #pragma unroll
    for (int j = 0; j < 4; j++) {
      gload16(Ag + agoff[j] + k0, &Ab[bufi][lbase[j]]);
      gload16(Bg + bgoff[j] + k0, &Bb[bufi][lbase[j]]);
    }
  };
  auto compute = [&](int bufi) {
    #pragma unroll
    for (int kk = 0; kk < 2; kk++) {
      int swz = ((kk * 4 + l4) ^ (l15 & 7)) * 8;
      bf16x8 a[4], b[4];
      #pragma unroll
      for (int m = 0; m < 4; m++)
        a[m] = ld_frag(&Ab[bufi][(wr * 64 + m * 16 + l15) * BK + swz]);
      #pragma unroll
      for (int n = 0; n < 4; n++)
        b[n] = ld_frag(&Bb[bufi][(wc * 64 + n * 16 + l15) * BK + swz]);
      #pragma unroll
      for (int m = 0; m < 4; m++)
        #pragma unroll
        for (int n = 0; n < 4; n++)
          acc[m][n] = mfma16(a[m], b[n], acc[m][n]);
    }
  };

  // prologue: 2 tiles in flight (16 loads/wave)
  stage(0, 0);
  stage(1, 1);

  int cur = 0;
  for (int kb = 0; kb < kiters - 2; kb++) {
    WAITVM(8);                         // this wave's buf[cur] loads landed
    __builtin_amdgcn_s_barrier();      // all waves' buf[cur] loads landed
    compute(cur);
    __builtin_amdgcn_s_barrier();      // all waves done reading buf[cur]
    stage(cur, kb + 2);
    cur ^= 1;
  }
  // tail: outstanding 16 -> 8 -> 0
  WAITVM(8);
  __builtin_amdgcn_s_barrier();
  compute(cur);
  cur ^= 1;
  WAITVM(0);
  __builtin_amdgcn_s_barrier();
  compute(cur);

  size_t obase = ((size_t)(ks * nl + l) * BATCH + mt * 128) * NH + nt * 128;
  if (OBF) {
    u16* Go = (u16*)args.G + obase;
    #pragma unroll
    for (int m = 0; m < 4; m++) {
      int row = wr * 64 + m * 16 + l4 * 4;
      #pragma unroll
      for (int n = 0; n < 4; n++) {
        int col = wc * 64 + n * 16 + l15;
        #pragma unroll
        for (int r = 0; r < 4; r++)
          Go[(size_t)(row + r) * NH + col] = f2bf(acc[m][n][r]);
      }
    }
  } else {
    float* Go = (float*)args.G + obase;
    #pragma unroll
    for (int m = 0; m < 4; m++) {
      int row = wr * 64 + m * 16 + l4 * 4;
      #pragma unroll
      for (int n = 0; n < 4; n++) {
        int col = wc * 64 + n * 16 + l15;
        #pragma unroll
        for (int r = 0; r < 4; r++)
          Go[(size_t)(row + r) * NH + col] = acc[m][n][r];
      }
    }
  }
}

// ---------------- element-wise sin chain ----------------
// hout[l] = sin(hout[l-1] + G0[l]+G1[l]+G2[l]+G3[l] + b[l]); bf16 partials
__global__ __launch_bounds__(256) void k_chain(const u16* __restrict__ Gp,
                                               const float* __restrict__ x_in,
                                               const float* __restrict__ brec,
                                               u16* __restrict__ hout) {
  int i = blockIdx.x * 256 + threadIdx.x;  // 131072 threads, 4 elems each
  int e = i * 4;
  int col = e & (NH - 1);
  f32x4 pre = *(const f32x4*)(x_in + e);
  #pragma unroll
  for (int l = 0; l < LAY; l++) {
    u16x4 g0 = *(const u16x4*)(Gp + (size_t)(0 * LAY + l) * (BATCH * NH) + e);
    u16x4 g1 = *(const u16x4*)(Gp + (size_t)(1 * LAY + l) * (BATCH * NH) + e);
    u16x4 g2 = *(const u16x4*)(Gp + (size_t)(2 * LAY + l) * (BATCH * NH) + e);
    u16x4 g3 = *(const u16x4*)(Gp + (size_t)(3 * LAY + l) * (BATCH * NH) + e);
    f32x4 bb = *(const f32x4*)(brec + l * NH + col);
    u16x4 hv;
    #pragma unroll
    for (int j = 0; j < 4; j++) {
      float v = fast_sin(pre[j] + (bf2f(g0[j]) + bf2f(g1[j])) +
                         (bf2f(g2[j]) + bf2f(g3[j])) + bb[j]);
      pre[j] = v;
      hv[j] = f2bf(v);
    }
    *(u16x4*)(hout + (size_t)l * (BATCH * NH) + e) = hv;
  }
}

// x_in = sum of 6 partial slices + bias (fp32 partials)
__global__ __launch_bounds__(256) void k_xin_fin(const float* __restrict__ Gp2,
                                                 const float* __restrict__ bin,
                                                 float* __restrict__ x_in) {
  int i = blockIdx.x * 256 + threadIdx.x;
  int e = i * 4;
  int col = e & (NH - 1);
  f32x4 s = *(const f32x4*)(bin + col);
  #pragma unroll
  for (int t = 0; t < 6; t++)
    s += *(const f32x4*)(Gp2 + (size_t)t * (BATCH * NH) + e);
  *(f32x4*)(x_in + e) = s;
}

// ---------------- output projection: out = h3 @ (Wh+Wl)^T + b ----------------
__global__ __launch_bounds__(64) void k_gemm_out(const u16* __restrict__ h3,
                                                 const u16* __restrict__ Wh,
                                                 const u16* __restrict__ Wl,
                                                 const float* __restrict__ bout,
                                                 float* __restrict__ out) {
  int bid = blockIdx.x;  // 128 = 8 mt x 16 nt
  int mt = bid & 7, nt = bid >> 3;
  int lane = threadIdx.x;
  int l15 = lane & 15, l4 = lane >> 4;
  f32x4 zero = {0.f, 0.f, 0.f, 0.f};
  f32x4 acc0 = zero, acc1 = zero;
  const u16* a0p = h3 + (size_t)(mt * 32 + l15) * NH + l4 * 8;
  const u16* a1p = a0p + 16 * NH;
  const u16* bhp = Wh + (size_t)(nt * 16 + l15) * NH + l4 * 8;
  const u16* blp = Wl + (size_t)(nt * 16 + l15) * NH + l4 * 8;
  for (int kb = 0; kb < 64; kb++) {
    bf16x8 a0 = ld_frag(a0p + kb * 32);
    bf16x8 a1 = ld_frag(a1p + kb * 32);
    bf16x8 bh = ld_frag(bhp + kb * 32);
    bf16x8 bl = ld_frag(blp + kb * 32);
    acc0 = mfma16(a0, bh, acc0);
    acc0 = mfma16(a0, bl, acc0);
    acc1 = mfma16(a1, bh, acc1);
    acc1 = mfma16(a1, bl, acc1);
  }
  float bo = bout[nt * 16 + l15];
  #pragma unroll
  for (int r = 0; r < 4; r++) {
    out[(size_t)(mt * 32 + l4 * 4 + r) * NOUT + nt * 16 + l15] = acc0[r] + bo;
    out[(size_t)(mt * 32 + 16 + l4 * 4 + r) * NOUT + nt * 16 + l15] = acc1[r] + bo;
  }
}

// ---------------- host ----------------

extern "C" void kernel_launch(void* const* d_in, const int* in_sizes, int n_in,
                              void* d_out, int out_size, void* d_ws, size_t ws_size,
                              hipStream_t stream) {
  const float* X     = (const float*)d_in[0];
  const float* Winw  = (const float*)d_in[1];
  const float* Winb  = (const float*)d_in[2];
  const float* Wrw   = (const float*)d_in[3];
  const float* Wrb   = (const float*)d_in[4];
  const float* Woutw = (const float*)d_in[5];
  const float* Woutb = (const float*)d_in[6];
  float* out = (float*)d_out;

  char* ws = (char*)d_ws;
  u16* Wb     = (u16*)(ws);                    // 32 MB  bf16 W_rec
  u16* h0     = (u16*)(ws + 33554432);         // 4 MB
  u16* h1     = (u16*)(ws + 37748736);         // 4 MB
  float* xin  = (float*)(ws + 41943040);       // 2 MB
  u16* Gp     = (u16*)(ws + 44040192);         // 16 MB bf16 (4 ks x 4 l)
  float* Gp2  = (float*)(ws + 60817408);       // 12 MB fp32 (2 ks x 3 terms)
  u16* Xhi    = (u16*)(ws + 73400320);         // 512 KB
  u16* Xlo    = (u16*)(ws + 73924608);         // 512 KB
  u16* Winh   = (u16*)(ws + 74448896);         // 4 MB
  u16* Winl   = (u16*)(ws + 78643200);         // 4 MB
  u16* Wouth  = (u16*)(ws + 82837504);         // 1 MB
  u16* Woutl  = (u16*)(ws + 83886080);         // 1 MB -> end 84934656

  // pack weights (every call; stateless)
  k_cvt<<<16384, 256, 0, stream>>>(Wrw, Wb, 4194304);
  k_split2<<<256, 256, 0, stream>>>(X, Xhi, Xlo, 65536);
  k_split2<<<2048, 256, 0, stream>>>(Winw, Winh, Winl, 524288);
  k_split2<<<512, 256, 0, stream>>>(Woutw, Wouth, Woutl, 131072);
  hipMemsetAsync(h0, 0, 4194304, stream);

  // x_in = X @ W_in^T (+bias), 3-term bf16 split, fp32 partials, split-K 2
  GemmArgs ax;
  ax.A[0] = Xhi; ax.A[1] = Xhi; ax.A[2] = Xlo; ax.A[3] = Xhi;
  ax.B[0] = Winh; ax.B[1] = Winl; ax.B[2] = Winh; ax.B[3] = Winh;
  ax.G = Gp2; ax.ldA = NIN; ax.ldB = NIN; ax.kiters = 8; ax.nl = 3;
  k_gemm<0, 2><<<192, 256, 0, stream>>>(ax);
  k_xin_fin<<<512, 256, 0, stream>>>(Gp2, Winb, xin);

  u16* hin = h0;
  u16* hout = h1;
  for (int t = 0; t < TSS; t++) {
    GemmArgs ar;
    for (int l = 0; l < 4; l++) {
      ar.A[l] = hin + (size_t)l * (BATCH * NH);
      ar.B[l] = Wb + (size_t)l * (NH * NH);
    }
    ar.G = Gp; ar.ldA = NH; ar.ldB = NH; ar.kiters = 8; ar.nl = 4;
    k_gemm<1, 4><<<512, 256, 0, stream>>>(ar);  // 2 blocks/CU
    k_chain<<<512, 256, 0, stream>>>(Gp, xin, Wrb, hout);
    u16* tmp = hin; hin = hout; hout = tmp;
  }

  k_gemm_out<<<128, 64, 0, stream>>>(hin + (size_t)3 * (BATCH * NH), Wouth, Woutl,
                                     Woutb, out);
}